// Round 1
// baseline (507.178 us; speedup 1.0000x reference)
//
#include <hip/hip_runtime.h>

// AttentionLayer: N=8, L=1024, D_MODEL=1024, H=16, d_head=64.
// out  = softmax(QK^T/8)V reshaped   (8,1024,1024) fp32
// attn = mean over heads of softmax  (8,1024,1024) fp32, after out.
//
// R6: coalescing fix (MFMA-friendly layouts, contiguous fragment loads).
// R7: occupancy fix. rocprof showed LDS_Block_Size=88KB -> 1 block/CU,
// Occupancy 47%, all pipes <16% busy: latency-bound with only 4 waves/SIMD
// and 512 blocks running as 2 sequential rounds. P32 (loop1-only, wave-
// private, transient) now ALIASES astage (loop2-only; cross-wave reads are
// barrier-ordered after every wave exits loop1), cutting LDS 88KB -> 68KB:
// 2 blocks/CU, 8 waves/SIMD, all 512 blocks co-resident in one round.
// __launch_bounds__ min-waves/EU 4 -> 8 (VGPR=52 fits <=64 budget).
// ws: 32 MB (bKw + bTw).

#define NB 8
#define LQ 1024
#define DM 1024
#define NH 16
#define DH 64
#define PW 40           // P32 row stride (shorts): 80 B, breaks pow2
#define AW 68           // attn stage row stride (floats): 272 B

typedef __attribute__((ext_vector_type(4))) float f32x4;
typedef __attribute__((ext_vector_type(8))) short bf16x8;
typedef __attribute__((ext_vector_type(4))) short bf16x4;

__device__ inline short f2bf(float f){
  unsigned u = __builtin_bit_cast(unsigned, f);
  u += 0x7fffu + ((u >> 16) & 1u);   // RNE (inputs finite)
  return (short)(u >> 16);
}

// ---------------- k0: fp32 -> bf16 into MFMA-friendly layouts ---------------
__global__ __launch_bounds__(256) void k0_convert(const float* __restrict__ in,
                                                  short* __restrict__ bKw,
                                                  short* __restrict__ bTw){
  __shared__ short tile[32][36];
  int b  = blockIdx.x;
  int n  = b >> 10;
  int lt = (b >> 5) & 31;          // s-tile of 32 == V window index
  int dt = b & 31;                 // d-tile of 32: head = dt>>1, half = dt&1
  int r  = threadIdx.x >> 3;       // 0..31
  int c4 = (threadIdx.x & 7) << 2; // 0,4,...,28
  size_t src = ((size_t)(n*LQ + lt*32 + r))*DM + dt*32 + c4;
  f32x4 f = *(const f32x4*)(in + src);
  short s0 = f2bf(f.x), s1 = f2bf(f.y), s2 = f2bf(f.z), s3 = f2bf(f.w);
  // head-major K/Q: bKw[((n*16 + h)*1024 + s)*64 + (dt&1)*32 + c]
  bf16x4 pk = {s0, s1, s2, s3};
  size_t kdst = ((size_t)((n*NH + (dt >> 1))*LQ + lt*32 + r))*DH + (dt & 1)*32 + c4;
  *(bf16x4*)(bKw + kdst) = pk;
  // transpose for V
  tile[c4+0][r] = s0; tile[c4+1][r] = s1; tile[c4+2][r] = s2; tile[c4+3][r] = s3;
  __syncthreads();
  bf16x4 t = *(const bf16x4*)(&tile[r][c4]);
  // win-tiled V: bTw[((n*32 + lt)*1024 + dt*32 + r)*32 + sl]
  size_t vdst = ((size_t)((n*32 + lt)*DM + dt*32 + r))*32 + c4;
  *(bf16x4*)(bTw + vdst) = t;
}

// ---------------- k2: one wave per head, barrier-free main loop --------------
// LDS: single 68KB arena. Per-wave slice [w*16*AW .. (w+1)*16*AW) floats:
//   loop1: first 1280 B hold that wave's P32 rows (write->read, same wave,
//          no cross-wave access, no barrier needed)
//   loop2: the full 4352 B slice holds the wave's scaled-attn stage; all
//          cross-wave reads happen after __syncthreads, which also orders
//          them after every wave's last P32 use (loop1 precedes loop2).
__global__ __launch_bounds__(1024, 8) void k2_attn(const short* __restrict__ bKw,
                                                   const short* __restrict__ bTw,
                                                   float* __restrict__ out,
                                                   float* __restrict__ attn){
  __shared__ float astage[NH*16*AW];    // 69632 B total (aliased by P rows)
  int tid  = threadIdx.x;
  int lane = tid & 63;
  int w    = tid >> 6;                  // wave id == head id
  int l16  = lane & 15;
  int quad = lane >> 4;
  int n  = blockIdx.x & 7;              // XCD swizzle
  int q0 = (blockIdx.x >> 3) << 4;

  const float CE = 0.1803368801111244f; // 0.125 * log2(e)
  const f32x4 vzero = {0.f, 0.f, 0.f, 0.f};

  // head-major bases: row s -> kb + s*64 (contiguous 2KB per 16-row frag pair)
  const short* kb = bKw + ((size_t)(n*NH + w))*LQ*DH + (size_t)l16*DH + quad*8;
  bf16x8 qf0 = *(const bf16x8*)(kb + (size_t)q0*DH);
  bf16x8 qf1 = *(const bf16x8*)(kb + (size_t)q0*DH + 32);

  float* Amine = &astage[(size_t)w*16*AW];
  short* Pmine = (short*)Amine;         // aliases first 1280 B of the slice

  f32x4 oacc[4];
  #pragma unroll
  for (int dt = 0; dt < 4; ++dt) oacc[dt] = vzero;
  float rsum = 0.f;

  // ---- loop1: QK + exp (unnormalized) + PV, NO barriers ----
  bf16x8 kf0 = *(const bf16x8*)kb;
  bf16x8 kf1 = *(const bf16x8*)(kb + 32);
  for (int win = 0; win < 16; ++win){
    #pragma unroll
    for (int sub = 0; sub < 4; ++sub){
      // prefetch next 16-s K slice (wraps harmlessly at the end)
      int nidx = (win*64 + sub*16 + 16) & 1023;
      const short* nkp = kb + (size_t)nidx*DH;
      bf16x8 nkf0 = *(const bf16x8*)nkp;
      bf16x8 nkf1 = *(const bf16x8*)(nkp + 32);
      f32x4 st = vzero;
      st = __builtin_amdgcn_mfma_f32_16x16x32_bf16(kf0, qf0, st, 0, 0, 0);
      st = __builtin_amdgcn_mfma_f32_16x16x32_bf16(kf1, qf1, st, 0, 0, 0);
      float e0 = __builtin_amdgcn_exp2f(st[0]*CE);
      float e1 = __builtin_amdgcn_exp2f(st[1]*CE);
      float e2 = __builtin_amdgcn_exp2f(st[2]*CE);
      float e3 = __builtin_amdgcn_exp2f(st[3]*CE);
      rsum += (e0 + e1) + (e2 + e3);
      bf16x4 pk = {f2bf(e0), f2bf(e1), f2bf(e2), f2bf(e3)};
      *(bf16x4*)(&Pmine[l16*PW + (sub & 1)*16 + quad*4]) = pk;
      if (sub & 1){
        int vwin = win*2 + (sub >> 1);       // 32-s V window index
        bf16x8 a01 = *(const bf16x8*)(&Pmine[l16*PW + quad*8]);
        #pragma unroll
        for (int dt = 0; dt < 4; ++dt){
          const short* vp = bTw + ((size_t)((n*32 + vwin)*DM + w*DH + dt*16 + l16))*32 + quad*8;
          bf16x8 vf = *(const bf16x8*)vp;
          oacc[dt] = __builtin_amdgcn_mfma_f32_16x16x32_bf16(a01, vf, oacc[dt], 0, 0, 0);
        }
      }
      kf0 = nkf0; kf1 = nkf1;
    }
  }

  // softmax normalizer for q = l16 (full row sum across quads)
  rsum += __shfl_xor(rsum, 16);
  rsum += __shfl_xor(rsum, 32);
  float ir  = 1.0f / rsum;
  float irs = ir * 0.0625f;             // folded 1/NH for attn

  // ---- O epilogue: oacc rows are q = q0 + quad*4 + j -> need ir of that q ----
  float irq[4];
  #pragma unroll
  for (int j = 0; j < 4; ++j) irq[j] = __shfl(ir, quad*4 + j);
  #pragma unroll
  for (int dt = 0; dt < 4; ++dt){
    float* op = out + ((size_t)(n*LQ + q0 + quad*4))*DM + w*DH + dt*16 + l16;
    op[0]      = oacc[dt][0] * irq[0];
    op[DM]     = oacc[dt][1] * irq[1];
    op[2*DM]   = oacc[dt][2] * irq[2];
    op[3*DM]   = oacc[dt][3] * irq[3];
  }

  // ---- loop2: recompute QK per 64-s window, scaled attn + cross-head reduce --
  for (int win = 0; win < 16; ++win){
    bf16x8 kw[4][2];
    #pragma unroll
    for (int sub = 0; sub < 4; ++sub){
      const short* kp = kb + (size_t)(win*64 + sub*16)*DH;
      kw[sub][0] = *(const bf16x8*)kp;
      kw[sub][1] = *(const bf16x8*)(kp + 32);
    }
    #pragma unroll
    for (int sub = 0; sub < 4; ++sub){
      f32x4 st = vzero;
      st = __builtin_amdgcn_mfma_f32_16x16x32_bf16(kw[sub][0], qf0, st, 0, 0, 0);
      st = __builtin_amdgcn_mfma_f32_16x16x32_bf16(kw[sub][1], qf1, st, 0, 0, 0);
      f32x4 av = {__builtin_amdgcn_exp2f(st[0]*CE) * irs,
                  __builtin_amdgcn_exp2f(st[1]*CE) * irs,
                  __builtin_amdgcn_exp2f(st[2]*CE) * irs,
                  __builtin_amdgcn_exp2f(st[3]*CE) * irs};
      *(f32x4*)(&Amine[l16*AW + sub*16 + quad*4]) = av;
    }
    __syncthreads();
    {
      int q = tid >> 6;
      int s = tid & 63;
      float sum = 0.f;
      #pragma unroll
      for (int ww = 0; ww < NH; ++ww)
        sum += astage[(size_t)ww*16*AW + q*AW + s];
      attn[((size_t)(n*LQ + q0 + q))*LQ + win*64 + s] = sum;
    }
    __syncthreads();
  }
}

extern "C" void kernel_launch(void* const* d_in, const int* in_sizes, int n_in,
                              void* d_out, int out_size, void* d_ws, size_t ws_size,
                              hipStream_t stream){
  const float* in = (const float*)d_in[0];
  float* out  = (float*)d_out;
  float* attn = out + (size_t)NB*LQ*DM;
  short* bKw = (short*)d_ws;
  short* bTw = bKw + (size_t)NB*LQ*DM;

  k0_convert<<<dim3(8192), dim3(256),  0, stream>>>(in, bKw, bTw);
  k2_attn   <<<dim3(512),  dim3(1024), 0, stream>>>(bKw, bTw, out, attn);
}

// Round 2
// 390.255 us; speedup vs baseline: 1.2996x; 1.2996x over previous
//
#include <hip/hip_runtime.h>

// AttentionLayer: N=8, L=1024, D_MODEL=1024, H=16, d_head=64.
// out  = softmax(QK^T/8)V reshaped   (8,1024,1024) fp32
// attn = mean over heads of softmax  (8,1024,1024) fp32, after out.
//
// R6: coalescing fix (MFMA-friendly layouts, contiguous fragment loads).
// R7: LDS aliasing (P32 aliases astage): 88KB -> 68KB, 2 blocks/CU possible.
//     BUT __launch_bounds__(1024,8) capped VGPRs to 32 -> scratch spills
//     (FETCH_SIZE 42MB -> 345MB, WRITE +610MB) -> 451us regression.
// R8: keep the LDS aliasing, revert min-waves/EU to 4. Compiler allocates
//     ~52 VGPRs (no spills); 52 <= 64 means HW still co-schedules 8
//     waves/SIMD = 2 blocks/CU now that LDS fits. Occupancy gain of R7
//     without the register-pressure catastrophe.
// ws: 32 MB (bKw + bTw).

#define NB 8
#define LQ 1024
#define DM 1024
#define NH 16
#define DH 64
#define PW 40           // P32 row stride (shorts): 80 B, breaks pow2
#define AW 68           // attn stage row stride (floats): 272 B

typedef __attribute__((ext_vector_type(4))) float f32x4;
typedef __attribute__((ext_vector_type(8))) short bf16x8;
typedef __attribute__((ext_vector_type(4))) short bf16x4;

__device__ inline short f2bf(float f){
  unsigned u = __builtin_bit_cast(unsigned, f);
  u += 0x7fffu + ((u >> 16) & 1u);   // RNE (inputs finite)
  return (short)(u >> 16);
}

// ---------------- k0: fp32 -> bf16 into MFMA-friendly layouts ---------------
__global__ __launch_bounds__(256) void k0_convert(const float* __restrict__ in,
                                                  short* __restrict__ bKw,
                                                  short* __restrict__ bTw){
  __shared__ short tile[32][36];
  int b  = blockIdx.x;
  int n  = b >> 10;
  int lt = (b >> 5) & 31;          // s-tile of 32 == V window index
  int dt = b & 31;                 // d-tile of 32: head = dt>>1, half = dt&1
  int r  = threadIdx.x >> 3;       // 0..31
  int c4 = (threadIdx.x & 7) << 2; // 0,4,...,28
  size_t src = ((size_t)(n*LQ + lt*32 + r))*DM + dt*32 + c4;
  f32x4 f = *(const f32x4*)(in + src);
  short s0 = f2bf(f.x), s1 = f2bf(f.y), s2 = f2bf(f.z), s3 = f2bf(f.w);
  // head-major K/Q: bKw[((n*16 + h)*1024 + s)*64 + (dt&1)*32 + c]
  bf16x4 pk = {s0, s1, s2, s3};
  size_t kdst = ((size_t)((n*NH + (dt >> 1))*LQ + lt*32 + r))*DH + (dt & 1)*32 + c4;
  *(bf16x4*)(bKw + kdst) = pk;
  // transpose for V
  tile[c4+0][r] = s0; tile[c4+1][r] = s1; tile[c4+2][r] = s2; tile[c4+3][r] = s3;
  __syncthreads();
  bf16x4 t = *(const bf16x4*)(&tile[r][c4]);
  // win-tiled V: bTw[((n*32 + lt)*1024 + dt*32 + r)*32 + sl]
  size_t vdst = ((size_t)((n*32 + lt)*DM + dt*32 + r))*32 + c4;
  *(bf16x4*)(bTw + vdst) = t;
}

// ---------------- k2: one wave per head, barrier-free main loop --------------
// LDS: single 68KB arena. Per-wave slice [w*16*AW .. (w+1)*16*AW) floats:
//   loop1: first 1280 B hold that wave's P32 rows (write->read, same wave,
//          no cross-wave access, no barrier needed)
//   loop2: the full 4352 B slice holds the wave's scaled-attn stage; all
//          cross-wave reads happen after __syncthreads, which also orders
//          them after every wave's last P32 use (loop1 precedes loop2).
__global__ __launch_bounds__(1024, 4) void k2_attn(const short* __restrict__ bKw,
                                                   const short* __restrict__ bTw,
                                                   float* __restrict__ out,
                                                   float* __restrict__ attn){
  __shared__ float astage[NH*16*AW];    // 69632 B total (aliased by P rows)
  int tid  = threadIdx.x;
  int lane = tid & 63;
  int w    = tid >> 6;                  // wave id == head id
  int l16  = lane & 15;
  int quad = lane >> 4;
  int n  = blockIdx.x & 7;              // XCD swizzle
  int q0 = (blockIdx.x >> 3) << 4;

  const float CE = 0.1803368801111244f; // 0.125 * log2(e)
  const f32x4 vzero = {0.f, 0.f, 0.f, 0.f};

  // head-major bases: row s -> kb + s*64 (contiguous 2KB per 16-row frag pair)
  const short* kb = bKw + ((size_t)(n*NH + w))*LQ*DH + (size_t)l16*DH + quad*8;
  bf16x8 qf0 = *(const bf16x8*)(kb + (size_t)q0*DH);
  bf16x8 qf1 = *(const bf16x8*)(kb + (size_t)q0*DH + 32);

  float* Amine = &astage[(size_t)w*16*AW];
  short* Pmine = (short*)Amine;         // aliases first 1280 B of the slice

  f32x4 oacc[4];
  #pragma unroll
  for (int dt = 0; dt < 4; ++dt) oacc[dt] = vzero;
  float rsum = 0.f;

  // ---- loop1: QK + exp (unnormalized) + PV, NO barriers ----
  bf16x8 kf0 = *(const bf16x8*)kb;
  bf16x8 kf1 = *(const bf16x8*)(kb + 32);
  for (int win = 0; win < 16; ++win){
    #pragma unroll
    for (int sub = 0; sub < 4; ++sub){
      // prefetch next 16-s K slice (wraps harmlessly at the end)
      int nidx = (win*64 + sub*16 + 16) & 1023;
      const short* nkp = kb + (size_t)nidx*DH;
      bf16x8 nkf0 = *(const bf16x8*)nkp;
      bf16x8 nkf1 = *(const bf16x8*)(nkp + 32);
      f32x4 st = vzero;
      st = __builtin_amdgcn_mfma_f32_16x16x32_bf16(kf0, qf0, st, 0, 0, 0);
      st = __builtin_amdgcn_mfma_f32_16x16x32_bf16(kf1, qf1, st, 0, 0, 0);
      float e0 = __builtin_amdgcn_exp2f(st[0]*CE);
      float e1 = __builtin_amdgcn_exp2f(st[1]*CE);
      float e2 = __builtin_amdgcn_exp2f(st[2]*CE);
      float e3 = __builtin_amdgcn_exp2f(st[3]*CE);
      rsum += (e0 + e1) + (e2 + e3);
      bf16x4 pk = {f2bf(e0), f2bf(e1), f2bf(e2), f2bf(e3)};
      *(bf16x4*)(&Pmine[l16*PW + (sub & 1)*16 + quad*4]) = pk;
      if (sub & 1){
        int vwin = win*2 + (sub >> 1);       // 32-s V window index
        bf16x8 a01 = *(const bf16x8*)(&Pmine[l16*PW + quad*8]);
        #pragma unroll
        for (int dt = 0; dt < 4; ++dt){
          const short* vp = bTw + ((size_t)((n*32 + vwin)*DM + w*DH + dt*16 + l16))*32 + quad*8;
          bf16x8 vf = *(const bf16x8*)vp;
          oacc[dt] = __builtin_amdgcn_mfma_f32_16x16x32_bf16(a01, vf, oacc[dt], 0, 0, 0);
        }
      }
      kf0 = nkf0; kf1 = nkf1;
    }
  }

  // softmax normalizer for q = l16 (full row sum across quads)
  rsum += __shfl_xor(rsum, 16);
  rsum += __shfl_xor(rsum, 32);
  float ir  = 1.0f / rsum;
  float irs = ir * 0.0625f;             // folded 1/NH for attn

  // ---- O epilogue: oacc rows are q = q0 + quad*4 + j -> need ir of that q ----
  float irq[4];
  #pragma unroll
  for (int j = 0; j < 4; ++j) irq[j] = __shfl(ir, quad*4 + j);
  #pragma unroll
  for (int dt = 0; dt < 4; ++dt){
    float* op = out + ((size_t)(n*LQ + q0 + quad*4))*DM + w*DH + dt*16 + l16;
    op[0]      = oacc[dt][0] * irq[0];
    op[DM]     = oacc[dt][1] * irq[1];
    op[2*DM]   = oacc[dt][2] * irq[2];
    op[3*DM]   = oacc[dt][3] * irq[3];
  }

  // ---- loop2: recompute QK per 64-s window, scaled attn + cross-head reduce --
  for (int win = 0; win < 16; ++win){
    bf16x8 kw[4][2];
    #pragma unroll
    for (int sub = 0; sub < 4; ++sub){
      const short* kp = kb + (size_t)(win*64 + sub*16)*DH;
      kw[sub][0] = *(const bf16x8*)kp;
      kw[sub][1] = *(const bf16x8*)(kp + 32);
    }
    #pragma unroll
    for (int sub = 0; sub < 4; ++sub){
      f32x4 st = vzero;
      st = __builtin_amdgcn_mfma_f32_16x16x32_bf16(kw[sub][0], qf0, st, 0, 0, 0);
      st = __builtin_amdgcn_mfma_f32_16x16x32_bf16(kw[sub][1], qf1, st, 0, 0, 0);
      f32x4 av = {__builtin_amdgcn_exp2f(st[0]*CE) * irs,
                  __builtin_amdgcn_exp2f(st[1]*CE) * irs,
                  __builtin_amdgcn_exp2f(st[2]*CE) * irs,
                  __builtin_amdgcn_exp2f(st[3]*CE) * irs};
      *(f32x4*)(&Amine[l16*AW + sub*16 + quad*4]) = av;
    }
    __syncthreads();
    {
      int q = tid >> 6;
      int s = tid & 63;
      float sum = 0.f;
      #pragma unroll
      for (int ww = 0; ww < NH; ++ww)
        sum += astage[(size_t)ww*16*AW + q*AW + s];
      attn[((size_t)(n*LQ + q0 + q))*LQ + win*64 + s] = sum;
    }
    __syncthreads();
  }
}

extern "C" void kernel_launch(void* const* d_in, const int* in_sizes, int n_in,
                              void* d_out, int out_size, void* d_ws, size_t ws_size,
                              hipStream_t stream){
  const float* in = (const float*)d_in[0];
  float* out  = (float*)d_out;
  float* attn = out + (size_t)NB*LQ*DM;
  short* bKw = (short*)d_ws;
  short* bTw = bKw + (size_t)NB*LQ*DM;

  k0_convert<<<dim3(8192), dim3(256),  0, stream>>>(in, bKw, bTw);
  k2_attn   <<<dim3(512),  dim3(1024), 0, stream>>>(bKw, bTw, out, attn);
}

// Round 3
// 254.036 us; speedup vs baseline: 1.9965x; 1.5362x over previous
//
#include <hip/hip_runtime.h>

// AttentionLayer: N=8, L=1024, D_MODEL=1024, H=16, d_head=64.
// out  = softmax(QK^T/8)V reshaped   (8,1024,1024) fp32
// attn = mean over heads of softmax  (8,1024,1024) fp32, after out.
//
// R6: coalescing fix (MFMA-friendly layouts, contiguous fragment loads).
// R7: LDS alias + reg cap -> spills, regressed. R8: alias only -> 329us,
//     occupancy stuck at 47%: unified VGPR+AGPR total >64 means 4 waves/SIMD
//     is a hard floor for this datapath. Occupancy is a dead end.
// R9: ILP instead of occupancy. Each block now covers 32 q-rows (2 MFMA
//     q-tiles per wave); grid 512 -> 256 (one round, every CU busy). K, V
//     and loop2 kw loads are SHARED between the two q-tiles (loads per unit
//     work halve); the two dependency chains interleave to fill stalls.
//     V is prefetched one sub early (issue at even sub, use at odd sub).
//     Loop2's attn stage moves to bf16 so 2 q-tiles fit: LDS = 139264 B.
// ws: 32 MB (bKw + bTw).

#define NB 8
#define LQ 1024
#define DM 1024
#define NH 16
#define DH 64
#define PW 40           // P32 row stride (shorts): 80 B, breaks pow2
#define AW 68           // attn stage row stride (shorts): 136 B

typedef __attribute__((ext_vector_type(4))) float f32x4;
typedef __attribute__((ext_vector_type(8))) short bf16x8;
typedef __attribute__((ext_vector_type(4))) short bf16x4;

__device__ inline short f2bf(float f){
  unsigned u = __builtin_bit_cast(unsigned, f);
  u += 0x7fffu + ((u >> 16) & 1u);   // RNE (inputs finite)
  return (short)(u >> 16);
}
__device__ inline float bf2f(short s){
  unsigned u = ((unsigned)(unsigned short)s) << 16;
  return __builtin_bit_cast(float, u);
}

// ---------------- k0: fp32 -> bf16 into MFMA-friendly layouts ---------------
__global__ __launch_bounds__(256) void k0_convert(const float* __restrict__ in,
                                                  short* __restrict__ bKw,
                                                  short* __restrict__ bTw){
  __shared__ short tile[32][36];
  int b  = blockIdx.x;
  int n  = b >> 10;
  int lt = (b >> 5) & 31;          // s-tile of 32 == V window index
  int dt = b & 31;                 // d-tile of 32: head = dt>>1, half = dt&1
  int r  = threadIdx.x >> 3;       // 0..31
  int c4 = (threadIdx.x & 7) << 2; // 0,4,...,28
  size_t src = ((size_t)(n*LQ + lt*32 + r))*DM + dt*32 + c4;
  f32x4 f = *(const f32x4*)(in + src);
  short s0 = f2bf(f.x), s1 = f2bf(f.y), s2 = f2bf(f.z), s3 = f2bf(f.w);
  // head-major K/Q: bKw[((n*16 + h)*1024 + s)*64 + (dt&1)*32 + c]
  bf16x4 pk = {s0, s1, s2, s3};
  size_t kdst = ((size_t)((n*NH + (dt >> 1))*LQ + lt*32 + r))*DH + (dt & 1)*32 + c4;
  *(bf16x4*)(bKw + kdst) = pk;
  // transpose for V
  tile[c4+0][r] = s0; tile[c4+1][r] = s1; tile[c4+2][r] = s2; tile[c4+3][r] = s3;
  __syncthreads();
  bf16x4 t = *(const bf16x4*)(&tile[r][c4]);
  // win-tiled V: bTw[((n*32 + lt)*1024 + dt*32 + r)*32 + sl]
  size_t vdst = ((size_t)((n*32 + lt)*DM + dt*32 + r))*32 + c4;
  *(bf16x4*)(bTw + vdst) = t;
}

// ---------------- k2: one wave per head, two q-tiles per wave ---------------
// LDS arena AS[2][NH*16*AW] shorts (139264 B):
//   loop1: first 1280 B of each wave's slice in half qt holds that tile's
//          P rows (wave-private, write->read same wave, no barriers).
//   loop2: half qt stages tile qt's scaled softmax (bf16); cross-wave reads
//          only after __syncthreads.
__global__ __launch_bounds__(1024, 4) void k2_attn(const short* __restrict__ bKw,
                                                   const short* __restrict__ bTw,
                                                   float* __restrict__ out,
                                                   float* __restrict__ attn){
  __shared__ short AS[2*NH*16*AW];      // 139264 B
  int tid  = threadIdx.x;
  int lane = tid & 63;
  int w    = tid >> 6;                  // wave id == head id
  int l16  = lane & 15;
  int quad = lane >> 4;
  int n  = blockIdx.x & 7;              // XCD swizzle: all blocks on XCD x share n=x
  int q0 = (blockIdx.x >> 3) << 5;      // 32 q-rows per block

  const float CE = 0.1803368801111244f; // 0.125 * log2(e)
  const f32x4 vzero = {0.f, 0.f, 0.f, 0.f};

  // head-major bases: row s -> kb + s*64 (contiguous 2KB per 16-row frag pair)
  const short* kb = bKw + ((size_t)(n*NH + w))*LQ*DH + (size_t)l16*DH + quad*8;
  bf16x8 qfA0 = *(const bf16x8*)(kb + (size_t)q0*DH);
  bf16x8 qfA1 = *(const bf16x8*)(kb + (size_t)q0*DH + 32);
  bf16x8 qfB0 = *(const bf16x8*)(kb + (size_t)(q0+16)*DH);
  bf16x8 qfB1 = *(const bf16x8*)(kb + (size_t)(q0+16)*DH + 32);

  short* PmineA = &AS[w*16*AW];
  short* PmineB = &AS[NH*16*AW + w*16*AW];

  f32x4 oaccA[4], oaccB[4];
  #pragma unroll
  for (int dt = 0; dt < 4; ++dt){ oaccA[dt] = vzero; oaccB[dt] = vzero; }
  float rsumA = 0.f, rsumB = 0.f;

  // ---- loop1: QK + exp (unnormalized) + PV, NO barriers ----
  bf16x8 kf0 = *(const bf16x8*)kb;
  bf16x8 kf1 = *(const bf16x8*)(kb + 32);
  bf16x8 vpre[4];
  for (int win = 0; win < 16; ++win){
    #pragma unroll
    for (int sub = 0; sub < 4; ++sub){
      // prefetch next 16-s K slice (wraps harmlessly at the end)
      int nidx = (win*64 + sub*16 + 16) & 1023;
      const short* nkp = kb + (size_t)nidx*DH;
      bf16x8 nkf0 = *(const bf16x8*)nkp;
      bf16x8 nkf1 = *(const bf16x8*)(nkp + 32);
      if ((sub & 1) == 0){
        // prefetch V for the window consumed at the NEXT (odd) sub
        int vwin = win*2 + (sub >> 1);
        #pragma unroll
        for (int dt = 0; dt < 4; ++dt){
          const short* vp = bTw + ((size_t)((n*32 + vwin)*DM + w*DH + dt*16 + l16))*32 + quad*8;
          vpre[dt] = *(const bf16x8*)vp;
        }
      }
      f32x4 stA = vzero, stB = vzero;
      stA = __builtin_amdgcn_mfma_f32_16x16x32_bf16(kf0, qfA0, stA, 0, 0, 0);
      stA = __builtin_amdgcn_mfma_f32_16x16x32_bf16(kf1, qfA1, stA, 0, 0, 0);
      stB = __builtin_amdgcn_mfma_f32_16x16x32_bf16(kf0, qfB0, stB, 0, 0, 0);
      stB = __builtin_amdgcn_mfma_f32_16x16x32_bf16(kf1, qfB1, stB, 0, 0, 0);
      float eA0 = __builtin_amdgcn_exp2f(stA[0]*CE);
      float eA1 = __builtin_amdgcn_exp2f(stA[1]*CE);
      float eA2 = __builtin_amdgcn_exp2f(stA[2]*CE);
      float eA3 = __builtin_amdgcn_exp2f(stA[3]*CE);
      float eB0 = __builtin_amdgcn_exp2f(stB[0]*CE);
      float eB1 = __builtin_amdgcn_exp2f(stB[1]*CE);
      float eB2 = __builtin_amdgcn_exp2f(stB[2]*CE);
      float eB3 = __builtin_amdgcn_exp2f(stB[3]*CE);
      rsumA += (eA0 + eA1) + (eA2 + eA3);
      rsumB += (eB0 + eB1) + (eB2 + eB3);
      bf16x4 pkA = {f2bf(eA0), f2bf(eA1), f2bf(eA2), f2bf(eA3)};
      bf16x4 pkB = {f2bf(eB0), f2bf(eB1), f2bf(eB2), f2bf(eB3)};
      *(bf16x4*)(&PmineA[l16*PW + (sub & 1)*16 + quad*4]) = pkA;
      *(bf16x4*)(&PmineB[l16*PW + (sub & 1)*16 + quad*4]) = pkB;
      if (sub & 1){
        bf16x8 a01A = *(const bf16x8*)(&PmineA[l16*PW + quad*8]);
        bf16x8 a01B = *(const bf16x8*)(&PmineB[l16*PW + quad*8]);
        #pragma unroll
        for (int dt = 0; dt < 4; ++dt){
          oaccA[dt] = __builtin_amdgcn_mfma_f32_16x16x32_bf16(a01A, vpre[dt], oaccA[dt], 0, 0, 0);
          oaccB[dt] = __builtin_amdgcn_mfma_f32_16x16x32_bf16(a01B, vpre[dt], oaccB[dt], 0, 0, 0);
        }
      }
      kf0 = nkf0; kf1 = nkf1;
    }
  }

  // softmax normalizer for q = l16 (full row sum across quads)
  rsumA += __shfl_xor(rsumA, 16);
  rsumA += __shfl_xor(rsumA, 32);
  rsumB += __shfl_xor(rsumB, 16);
  rsumB += __shfl_xor(rsumB, 32);
  float irA  = 1.0f / rsumA;
  float irB  = 1.0f / rsumB;
  float irsA = irA * 0.0625f;           // folded 1/NH for attn
  float irsB = irB * 0.0625f;

  // ---- O epilogue: oacc rows are q = quad*4 + j -> need ir of that q ----
  float irqA[4], irqB[4];
  #pragma unroll
  for (int j = 0; j < 4; ++j){
    irqA[j] = __shfl(irA, quad*4 + j);
    irqB[j] = __shfl(irB, quad*4 + j);
  }
  #pragma unroll
  for (int dt = 0; dt < 4; ++dt){
    float* opA = out + ((size_t)(n*LQ + q0 + quad*4))*DM + w*DH + dt*16 + l16;
    opA[0]      = oaccA[dt][0] * irqA[0];
    opA[DM]     = oaccA[dt][1] * irqA[1];
    opA[2*DM]   = oaccA[dt][2] * irqA[2];
    opA[3*DM]   = oaccA[dt][3] * irqA[3];
    float* opB = opA + (size_t)16*DM;
    opB[0]      = oaccB[dt][0] * irqB[0];
    opB[DM]     = oaccB[dt][1] * irqB[1];
    opB[2*DM]   = oaccB[dt][2] * irqB[2];
    opB[3*DM]   = oaccB[dt][3] * irqB[3];
  }

  // ---- loop2: recompute QK per 64-s window, bf16 attn stage + reduce ----
  short* AmineA = PmineA;               // tile A stage (half 0)
  short* AmineB = PmineB;               // tile B stage (half 1)
  for (int win = 0; win < 16; ++win){
    bf16x8 kw[4][2];
    #pragma unroll
    for (int sub = 0; sub < 4; ++sub){
      const short* kp = kb + (size_t)(win*64 + sub*16)*DH;
      kw[sub][0] = *(const bf16x8*)kp;
      kw[sub][1] = *(const bf16x8*)(kp + 32);
    }
    #pragma unroll
    for (int sub = 0; sub < 4; ++sub){
      f32x4 stA = vzero, stB = vzero;
      stA = __builtin_amdgcn_mfma_f32_16x16x32_bf16(kw[sub][0], qfA0, stA, 0, 0, 0);
      stA = __builtin_amdgcn_mfma_f32_16x16x32_bf16(kw[sub][1], qfA1, stA, 0, 0, 0);
      stB = __builtin_amdgcn_mfma_f32_16x16x32_bf16(kw[sub][0], qfB0, stB, 0, 0, 0);
      stB = __builtin_amdgcn_mfma_f32_16x16x32_bf16(kw[sub][1], qfB1, stB, 0, 0, 0);
      bf16x4 avA = {f2bf(__builtin_amdgcn_exp2f(stA[0]*CE) * irsA),
                    f2bf(__builtin_amdgcn_exp2f(stA[1]*CE) * irsA),
                    f2bf(__builtin_amdgcn_exp2f(stA[2]*CE) * irsA),
                    f2bf(__builtin_amdgcn_exp2f(stA[3]*CE) * irsA)};
      bf16x4 avB = {f2bf(__builtin_amdgcn_exp2f(stB[0]*CE) * irsB),
                    f2bf(__builtin_amdgcn_exp2f(stB[1]*CE) * irsB),
                    f2bf(__builtin_amdgcn_exp2f(stB[2]*CE) * irsB),
                    f2bf(__builtin_amdgcn_exp2f(stB[3]*CE) * irsB)};
      *(bf16x4*)(&AmineA[l16*AW + sub*16 + quad*4]) = avA;
      *(bf16x4*)(&AmineB[l16*AW + sub*16 + quad*4]) = avB;
    }
    __syncthreads();
    {
      int qr = tid >> 6;                // 0..15
      int s  = tid & 63;                // 0..63
      float sum0 = 0.f, sum1 = 0.f;
      #pragma unroll
      for (int ww = 0; ww < NH; ++ww){
        sum0 += bf2f(AS[ww*16*AW + qr*AW + s]);
        sum1 += bf2f(AS[NH*16*AW + ww*16*AW + qr*AW + s]);
      }
      attn[((size_t)(n*LQ + q0 + qr))*LQ + win*64 + s]      = sum0;
      attn[((size_t)(n*LQ + q0 + 16 + qr))*LQ + win*64 + s] = sum1;
    }
    __syncthreads();
  }
}

extern "C" void kernel_launch(void* const* d_in, const int* in_sizes, int n_in,
                              void* d_out, int out_size, void* d_ws, size_t ws_size,
                              hipStream_t stream){
  const float* in = (const float*)d_in[0];
  float* out  = (float*)d_out;
  float* attn = out + (size_t)NB*LQ*DM;
  short* bKw = (short*)d_ws;
  short* bTw = bKw + (size_t)NB*LQ*DM;

  k0_convert<<<dim3(8192), dim3(256),  0, stream>>>(in, bKw, bTw);
  k2_attn   <<<dim3(256),  dim3(1024), 0, stream>>>(bKw, bTw, out, attn);
}

// Round 4
// 251.199 us; speedup vs baseline: 2.0190x; 1.0113x over previous
//
#include <hip/hip_runtime.h>

// AttentionLayer: N=8, L=1024, D_MODEL=1024, H=16, d_head=64.
// out  = softmax(QK^T/8)V reshaped   (8,1024,1024) fp32
// attn = mean over heads of softmax  (8,1024,1024) fp32, after out.
//
// R9: 2 q-tiles/wave (ILP), shared K/V loads -> 185us k2, still latency-bound
//     (MfmaUtil 11%, VALU 32%): dominant chain = P round-trip through LDS
//     (ds_write -> lgkm wait -> ds_read -> wait -> PV MFMA) per 32-s window.
// R10: eliminate the P LDS round-trip entirely via PERMUTED K fragments.
//     A-fragment row r is supplied by lanes l16==r but appears in D at
//     row quad*4+j. Loading K-row s=(r>>2)*8+(r&3) (+4 for the odd frag)
//     makes the QK output land at P[q=l16][s=quad*8+j] -- exactly the PV
//     A-fragment layout. Two packed st vectors concatenate straight into
//     the PV A operand: zero cross-lane movement, zero LDS, no waits.
//     Also: f2bf bit-hack packs -> v_cvt_pk_bf16_f32 (4 ops vs ~32).
//     Loop2 unchanged (standard contiguous fragments, own K loads).
// ws: 32 MB (bKw + bTw).

#define NB 8
#define LQ 1024
#define DM 1024
#define NH 16
#define DH 64
#define AW 68           // attn stage row stride (shorts): 136 B

typedef __attribute__((ext_vector_type(4))) float f32x4;
typedef __attribute__((ext_vector_type(8))) short bf16x8;
typedef __attribute__((ext_vector_type(4))) short bf16x4;
typedef __attribute__((ext_vector_type(4))) int   i32x4;
typedef __attribute__((ext_vector_type(2))) int   i32x2;

__device__ inline short f2bf(float f){
  unsigned u = __builtin_bit_cast(unsigned, f);
  u += 0x7fffu + ((u >> 16) & 1u);   // RNE (inputs finite)
  return (short)(u >> 16);
}
__device__ inline float bf2f(short s){
  unsigned u = ((unsigned)(unsigned short)s) << 16;
  return __builtin_bit_cast(float, u);
}
__device__ inline int cvt_pk_bf16(float lo, float hi){
  int r;
  asm("v_cvt_pk_bf16_f32 %0, %1, %2" : "=v"(r) : "v"(lo), "v"(hi));
  return r;
}

// ---------------- k0: fp32 -> bf16 into MFMA-friendly layouts ---------------
__global__ __launch_bounds__(256) void k0_convert(const float* __restrict__ in,
                                                  short* __restrict__ bKw,
                                                  short* __restrict__ bTw){
  __shared__ short tile[32][36];
  int b  = blockIdx.x;
  int n  = b >> 10;
  int lt = (b >> 5) & 31;          // s-tile of 32 == V window index
  int dt = b & 31;                 // d-tile of 32: head = dt>>1, half = dt&1
  int r  = threadIdx.x >> 3;       // 0..31
  int c4 = (threadIdx.x & 7) << 2; // 0,4,...,28
  size_t src = ((size_t)(n*LQ + lt*32 + r))*DM + dt*32 + c4;
  f32x4 f = *(const f32x4*)(in + src);
  short s0 = f2bf(f.x), s1 = f2bf(f.y), s2 = f2bf(f.z), s3 = f2bf(f.w);
  // head-major K/Q: bKw[((n*16 + h)*1024 + s)*64 + (dt&1)*32 + c]
  bf16x4 pk = {s0, s1, s2, s3};
  size_t kdst = ((size_t)((n*NH + (dt >> 1))*LQ + lt*32 + r))*DH + (dt & 1)*32 + c4;
  *(bf16x4*)(bKw + kdst) = pk;
  // transpose for V
  tile[c4+0][r] = s0; tile[c4+1][r] = s1; tile[c4+2][r] = s2; tile[c4+3][r] = s3;
  __syncthreads();
  bf16x4 t = *(const bf16x4*)(&tile[r][c4]);
  // win-tiled V: bTw[((n*32 + lt)*1024 + dt*32 + r)*32 + sl]
  size_t vdst = ((size_t)((n*32 + lt)*DM + dt*32 + r))*32 + c4;
  *(bf16x4*)(bTw + vdst) = t;
}

// ---------------- k2: one wave per head, two q-tiles per wave ---------------
// LDS arena AS[2][NH*16*AW] shorts (69632 B): loop2 attn staging only.
__global__ __launch_bounds__(1024, 4) void k2_attn(const short* __restrict__ bKw,
                                                   const short* __restrict__ bTw,
                                                   float* __restrict__ out,
                                                   float* __restrict__ attn){
  __shared__ short AS[2*NH*16*AW];      // 69632 B
  int tid  = threadIdx.x;
  int lane = tid & 63;
  int w    = tid >> 6;                  // wave id == head id
  int l16  = lane & 15;
  int quad = lane >> 4;
  int n  = blockIdx.x & 7;              // XCD swizzle: all blocks on XCD x share n=x
  int q0 = (blockIdx.x >> 3) << 5;      // 32 q-rows per block

  const float CE = 0.1803368801111244f; // 0.125 * log2(e)
  const f32x4 vzero = {0.f, 0.f, 0.f, 0.f};

  size_t hb = ((size_t)(n*NH + w))*LQ*DH;
  // standard fragment base (Q loads, loop2 K loads): row s -> kb + s*64
  const short* kb  = bKw + hb + (size_t)l16*DH + quad*8;
  // permuted fragment base (loop1 K loads): lane l16=r supplies row (r>>2)*8+(r&3)
  const short* kbp = bKw + hb + (size_t)((l16 >> 2)*8 + (l16 & 3))*DH + quad*8;

  bf16x8 qfA0 = *(const bf16x8*)(kb + (size_t)q0*DH);
  bf16x8 qfA1 = *(const bf16x8*)(kb + (size_t)q0*DH + 32);
  bf16x8 qfB0 = *(const bf16x8*)(kb + (size_t)(q0+16)*DH);
  bf16x8 qfB1 = *(const bf16x8*)(kb + (size_t)(q0+16)*DH + 32);

  f32x4 oaccA[4], oaccB[4];
  #pragma unroll
  for (int dt = 0; dt < 4; ++dt){ oaccA[dt] = vzero; oaccB[dt] = vzero; }
  float rsumA = 0.f, rsumB = 0.f;

  // ---- loop1: QK + exp (unnormalized) + PV, no barriers, no LDS ----
  // fragment f: s-offset t = (f>>1)*32 + (f&1)*4; covers rows t + perm set.
  bf16x8 kf0 = *(const bf16x8*)kbp;            // f=0 -> t=0
  bf16x8 kf1 = *(const bf16x8*)(kbp + 32);
  bf16x8 vpre[4];
  int paA0 = 0, paA1 = 0, paB0 = 0, paB1 = 0;  // packed bf16 from even f
  for (int f = 0; f < 64; ++f){
    int fn = (f + 1) & 63;
    int tn = (fn >> 1)*32 + (fn & 1)*4;
    const short* nkp = kbp + (size_t)tn*DH;
    bf16x8 nkf0 = *(const bf16x8*)nkp;
    bf16x8 nkf1 = *(const bf16x8*)(nkp + 32);
    if ((f & 1) == 0){
      // prefetch V for the 32-s window consumed at the next (odd) f
      int vwin = f >> 1;
      #pragma unroll
      for (int dt = 0; dt < 4; ++dt){
        const short* vp = bTw + ((size_t)((n*32 + vwin)*DM + w*DH + dt*16 + l16))*32 + quad*8;
        vpre[dt] = *(const bf16x8*)vp;
      }
    }
    f32x4 stA = vzero, stB = vzero;
    stA = __builtin_amdgcn_mfma_f32_16x16x32_bf16(kf0, qfA0, stA, 0, 0, 0);
    stA = __builtin_amdgcn_mfma_f32_16x16x32_bf16(kf1, qfA1, stA, 0, 0, 0);
    stB = __builtin_amdgcn_mfma_f32_16x16x32_bf16(kf0, qfB0, stB, 0, 0, 0);
    stB = __builtin_amdgcn_mfma_f32_16x16x32_bf16(kf1, qfB1, stB, 0, 0, 0);
    float eA0 = __builtin_amdgcn_exp2f(stA[0]*CE);
    float eA1 = __builtin_amdgcn_exp2f(stA[1]*CE);
    float eA2 = __builtin_amdgcn_exp2f(stA[2]*CE);
    float eA3 = __builtin_amdgcn_exp2f(stA[3]*CE);
    float eB0 = __builtin_amdgcn_exp2f(stB[0]*CE);
    float eB1 = __builtin_amdgcn_exp2f(stB[1]*CE);
    float eB2 = __builtin_amdgcn_exp2f(stB[2]*CE);
    float eB3 = __builtin_amdgcn_exp2f(stB[3]*CE);
    rsumA += (eA0 + eA1) + (eA2 + eA3);
    rsumB += (eB0 + eB1) + (eB2 + eB3);
    int dA0 = cvt_pk_bf16(eA0, eA1), dA1 = cvt_pk_bf16(eA2, eA3);
    int dB0 = cvt_pk_bf16(eB0, eB1), dB1 = cvt_pk_bf16(eB2, eB3);
    if ((f & 1) == 0){
      paA0 = dA0; paA1 = dA1; paB0 = dB0; paB1 = dB1;
    } else {
      // A-fragment k=quad*8+j: elems 0-3 from even f (s+0..3), 4-7 odd (s+4..7)
      i32x4 ta = {paA0, paA1, dA0, dA1};
      i32x4 tb = {paB0, paB1, dB0, dB1};
      bf16x8 a01A = __builtin_bit_cast(bf16x8, ta);
      bf16x8 a01B = __builtin_bit_cast(bf16x8, tb);
      #pragma unroll
      for (int dt = 0; dt < 4; ++dt){
        oaccA[dt] = __builtin_amdgcn_mfma_f32_16x16x32_bf16(a01A, vpre[dt], oaccA[dt], 0, 0, 0);
        oaccB[dt] = __builtin_amdgcn_mfma_f32_16x16x32_bf16(a01B, vpre[dt], oaccB[dt], 0, 0, 0);
      }
    }
    kf0 = nkf0; kf1 = nkf1;
  }

  // softmax normalizer for q = l16 (full row sum across quads)
  rsumA += __shfl_xor(rsumA, 16);
  rsumA += __shfl_xor(rsumA, 32);
  rsumB += __shfl_xor(rsumB, 16);
  rsumB += __shfl_xor(rsumB, 32);
  float irA  = 1.0f / rsumA;
  float irB  = 1.0f / rsumB;
  float irsA = irA * 0.0625f;           // folded 1/NH for attn
  float irsB = irB * 0.0625f;

  // ---- O epilogue: oacc rows are q = quad*4 + j -> need ir of that q ----
  float irqA[4], irqB[4];
  #pragma unroll
  for (int j = 0; j < 4; ++j){
    irqA[j] = __shfl(irA, quad*4 + j);
    irqB[j] = __shfl(irB, quad*4 + j);
  }
  #pragma unroll
  for (int dt = 0; dt < 4; ++dt){
    float* opA = out + ((size_t)(n*LQ + q0 + quad*4))*DM + w*DH + dt*16 + l16;
    opA[0]      = oaccA[dt][0] * irqA[0];
    opA[DM]     = oaccA[dt][1] * irqA[1];
    opA[2*DM]   = oaccA[dt][2] * irqA[2];
    opA[3*DM]   = oaccA[dt][3] * irqA[3];
    float* opB = opA + (size_t)16*DM;
    opB[0]      = oaccB[dt][0] * irqB[0];
    opB[DM]     = oaccB[dt][1] * irqB[1];
    opB[2*DM]   = oaccB[dt][2] * irqB[2];
    opB[3*DM]   = oaccB[dt][3] * irqB[3];
  }

  // ---- loop2: recompute QK per 64-s window, bf16 attn stage + reduce ----
  short* AmineA = &AS[w*16*AW];
  short* AmineB = &AS[NH*16*AW + w*16*AW];
  for (int win = 0; win < 16; ++win){
    bf16x8 kw[4][2];
    #pragma unroll
    for (int sub = 0; sub < 4; ++sub){
      const short* kp = kb + (size_t)(win*64 + sub*16)*DH;
      kw[sub][0] = *(const bf16x8*)kp;
      kw[sub][1] = *(const bf16x8*)(kp + 32);
    }
    #pragma unroll
    for (int sub = 0; sub < 4; ++sub){
      f32x4 stA = vzero, stB = vzero;
      stA = __builtin_amdgcn_mfma_f32_16x16x32_bf16(kw[sub][0], qfA0, stA, 0, 0, 0);
      stA = __builtin_amdgcn_mfma_f32_16x16x32_bf16(kw[sub][1], qfA1, stA, 0, 0, 0);
      stB = __builtin_amdgcn_mfma_f32_16x16x32_bf16(kw[sub][0], qfB0, stB, 0, 0, 0);
      stB = __builtin_amdgcn_mfma_f32_16x16x32_bf16(kw[sub][1], qfB1, stB, 0, 0, 0);
      float gA0 = __builtin_amdgcn_exp2f(stA[0]*CE) * irsA;
      float gA1 = __builtin_amdgcn_exp2f(stA[1]*CE) * irsA;
      float gA2 = __builtin_amdgcn_exp2f(stA[2]*CE) * irsA;
      float gA3 = __builtin_amdgcn_exp2f(stA[3]*CE) * irsA;
      float gB0 = __builtin_amdgcn_exp2f(stB[0]*CE) * irsB;
      float gB1 = __builtin_amdgcn_exp2f(stB[1]*CE) * irsB;
      float gB2 = __builtin_amdgcn_exp2f(stB[2]*CE) * irsB;
      float gB3 = __builtin_amdgcn_exp2f(stB[3]*CE) * irsB;
      i32x2 wvA = {cvt_pk_bf16(gA0, gA1), cvt_pk_bf16(gA2, gA3)};
      i32x2 wvB = {cvt_pk_bf16(gB0, gB1), cvt_pk_bf16(gB2, gB3)};
      *(i32x2*)(&AmineA[l16*AW + sub*16 + quad*4]) = wvA;
      *(i32x2*)(&AmineB[l16*AW + sub*16 + quad*4]) = wvB;
    }
    __syncthreads();
    {
      int qr = tid >> 6;                // 0..15
      int s  = tid & 63;                // 0..63
      float sum0 = 0.f, sum1 = 0.f;
      #pragma unroll
      for (int ww = 0; ww < NH; ++ww){
        sum0 += bf2f(AS[ww*16*AW + qr*AW + s]);
        sum1 += bf2f(AS[NH*16*AW + ww*16*AW + qr*AW + s]);
      }
      attn[((size_t)(n*LQ + q0 + qr))*LQ + win*64 + s]      = sum0;
      attn[((size_t)(n*LQ + q0 + 16 + qr))*LQ + win*64 + s] = sum1;
    }
    __syncthreads();
  }
}

extern "C" void kernel_launch(void* const* d_in, const int* in_sizes, int n_in,
                              void* d_out, int out_size, void* d_ws, size_t ws_size,
                              hipStream_t stream){
  const float* in = (const float*)d_in[0];
  float* out  = (float*)d_out;
  float* attn = out + (size_t)NB*LQ*DM;
  short* bKw = (short*)d_ws;
  short* bTw = bKw + (size_t)NB*LQ*DM;

  k0_convert<<<dim3(8192), dim3(256),  0, stream>>>(in, bKw, bTw);
  k2_attn   <<<dim3(256),  dim3(1024), 0, stream>>>(bKw, bTw, out, attn);
}